// Round 9
// baseline (1951.705 us; speedup 1.0000x reference)
//
#include <hip/hip_runtime.h>

#define T_STEPS 1000
#define N_IN    700
#define N_HID   4096
#define N_OUT   20
#define NBLK    256   // main-loop blocks: 1 wave, 16 neurons each
#define NPB     16    // neurons per block

typedef unsigned int u32x4 __attribute__((ext_vector_type(4)));
typedef unsigned int u32x2 __attribute__((ext_vector_type(2)));

// 4B device-coherent record ops; waitcnt INSIDE asm (no live in-flight regs)
__device__ __forceinline__ unsigned load_rec4(const unsigned* p) {
    unsigned r;
    asm volatile("global_load_dword %0, %1, off sc0 sc1\n\t"
                 "s_waitcnt vmcnt(0)"
                 : "=v"(r) : "v"(p) : "memory");
    return r;
}
__device__ __forceinline__ void store_rec4(unsigned* p, unsigned v) {
    asm volatile("global_store_dword %0, %1, off sc0 sc1"
                 :: "v"(p), "v"(v) : "memory");
}

// ---------------------------------------------------------------------------
// w1t[c*4096 + r] = (int8) w1[r*700 + c]
__global__ __launch_bounds__(256) void k_transpose_i8(
    const int* __restrict__ in, signed char* __restrict__ out,
    int R, int C, int out_stride)
{
    __shared__ signed char tile[32][33];
    const int cx = blockIdx.x * 32;
    const int ry = blockIdx.y * 32;
    const int tx = threadIdx.x;
    const int ty = threadIdx.y;
#pragma unroll
    for (int r = 0; r < 4; ++r) {
        int row = ry + ty + r * 8;
        int col = cx + tx;
        if (row < R && col < C)
            tile[ty + r * 8][tx] = (signed char)in[(size_t)row * C + col];
    }
    __syncthreads();
#pragma unroll
    for (int r = 0; r < 4; ++r) {
        int c   = cx + ty + r * 8;
        int row = ry + tx;
        if (c < C && row < R)
            out[(size_t)c * out_stride + row] = tile[tx][ty + r * 8];
    }
}

// ---------------------------------------------------------------------------
// v1n[b][k] = 8B row: 16 nibbles = (v1[b*16+j][k] + 8), j=0..15
__global__ __launch_bounds__(256) void k_prep_v1n(
    const int* __restrict__ in, unsigned char* __restrict__ out)
{
    __shared__ unsigned char tile[16][64];
    const int k0 = blockIdx.x * 64;
    const int b  = blockIdx.y;
    const int t  = threadIdx.x;
    const int kk = t & 63;
#pragma unroll
    for (int r = 0; r < 4; ++r) {
        int hl = (t >> 6) + r * 4;     // 0..15
        tile[hl][kk] = (unsigned char)(in[(size_t)(b * NPB + hl) * N_HID + k0 + kk] + 8);
    }
    __syncthreads();
    if (t < 64) {
        unsigned w0 = 0, w1 = 0;
#pragma unroll
        for (int j = 0; j < 8; ++j) w0 |= (unsigned)tile[j][t] << (4 * j);
#pragma unroll
        for (int j = 0; j < 8; ++j) w1 |= (unsigned)tile[8 + j][t] << (4 * j);
        u32x2 v = {w0, w1};
        *(u32x2*)(out + ((size_t)b << 15) + ((size_t)(k0 + t) << 3)) = v;
    }
}

// ---------------------------------------------------------------------------
// in_all2[b][t][16]: in_all2[(h>>4)*T*16 + t*16 + (h&15)]
__global__ __launch_bounds__(256) void k_inall(
    const signed char* __restrict__ w1t,   // [N_IN][N_HID]
    const int* __restrict__ spk,           // [T][N_IN]
    short* __restrict__ in_all2)           // [256][T][16]
{
    __shared__ int s_spk[16][N_IN];
    const int t0 = blockIdx.y * 16;
    const int tcnt = min(16, T_STEPS - t0);
    const int tid = threadIdx.x;
    for (int b = 0; b < tcnt; ++b)
        for (int i = tid; i < N_IN; i += 256)
            s_spk[b][i] = spk[(size_t)(t0 + b) * N_IN + i];
    __syncthreads();
    const int h = blockIdx.x * 256 + tid;
    int acc[16];
#pragma unroll
    for (int b = 0; b < 16; ++b) acc[b] = 0;
    for (int i = 0; i < N_IN; ++i) {
        int w = (int)w1t[(size_t)i * N_HID + h];
#pragma unroll
        for (int b = 0; b < 16; ++b) acc[b] += w * s_spk[b][i];
    }
    const size_t base = (size_t)(h >> 4) * (T_STEPS * NPB) + (h & 15);
    for (int b = 0; b < tcnt; ++b)
        in_all2[base + (size_t)(t0 + b) * NPB] = (short)acc[b];
}

// ---------------------------------------------------------------------------
// Main LIF loop: 256 blocks x 1 wave x 16 neurons, weights (nibble) in LDS,
// no barriers. pub[r] = 0x10000|mask16(out(r)) published at top of iter r-1;
// row t prefetched via global_load_lds (1KB), drained by vmcnt(0) at next top.
// Gather: dummy-padded uniform 16-row blocks (b = m?ctz:zero_row, no branch),
// two-level u8->u16 packed accumulation (5 VALU per u32, exact).
// Reduction: reduce-scatter butterfly (16 shfl) — lane ends with its neuron.
__global__ __launch_bounds__(64) void k_main(
    const short* __restrict__ in_all2,      // [256][T][16]
    const u32x2* __restrict__ v1n,          // [256][4096] 8B nibble rows
    unsigned* __restrict__ pub)             // [T+1][256], zeroed
{
    const int lane = threadIdx.x;
    const int bid  = blockIdx.x;
    const int j    = lane & 15;             // mirrored neuron index

    __shared__ u32x2 s_w[N_HID + 1];        // 32KB weight slice + zero row
    __shared__ u32x4 s_rec[2][64];          // double-buffered record rows, 2KB

    // ---- load weight slice once (coalesced 8B x 64 lanes per iter) ----
    {
        const u32x2* src = v1n + ((size_t)bid << 12);
        for (int r = lane; r < N_HID; r += 64) s_w[r] = src[r];
        if (lane == 0) { u32x2 z = {0u, 0u}; s_w[N_HID] = z; }
    }
    asm volatile("s_waitcnt vmcnt(0) lgkmcnt(0)" ::: "memory");

    if (lane == 0) store_rec4(pub + bid, 0x10000u);   // row 0: out(0)=0

    // lookahead state: mm = m'(t), synv = syn(t-1), out_t = out(t)
    int mm = 0, synv = 0, out_t = 0;
    const short* in_base = in_all2 + (size_t)bid * (T_STEPS * NPB) + j;
    const u32x2* wl = s_w + (lane << 6);
    const int bz = N_HID - (lane << 6);     // per-lane index of the zero row
    const unsigned M4 = 0x0F0F0F0Fu, M8 = 0x00FF00FFu;
    const int j0 = j & 1, j1 = j & 2, j3 = j & 8;

    for (int t = 0; t < T_STEPS; ++t) {
        const int cur = t & 1;
        // drain prev iter's prefetch (and store/in_cur; all >=1 iter old)
        asm volatile("s_waitcnt vmcnt(0)" ::: "memory");
        __builtin_amdgcn_sched_barrier(0);

        // ---- publish out(t+1) from local state ----
        int mem_t = (mm - (mm >> 3)) + synv;
        int mnext = out_t ? 0 : mem_t;
        int out_n = (mnext - 1 > 0) ? 1 : 0;
        unsigned om = (unsigned)__ballot(out_n) & 0xFFFFu;
        if (lane == 0) store_rec4(pub + (size_t)(t + 1) * NBLK + bid, 0x10000u | om);
        mm = mnext; out_t = out_n;

        int in_cur = (int)in_base[t * NPB];

        // ---- prefetch row t (for iter t+1): 64 lanes x 16B = 1KB ----
        __builtin_amdgcn_global_load_lds(
            (const void*)(pub + (size_t)t * NBLK + (lane << 2)),
            (void*)&s_rec[cur ^ 1][0], 16, 0, /*sc0|sc1*/ 17);

        // ---- consume row t-1: this lane's 4 records -> 64-bit k-mask ----
        unsigned mlo = 0, mhi = 0;
        if (t > 0) {
            u32x4 q = s_rec[cur][lane];
            if (((q.x & q.y & q.z & q.w) & 0x10000u) == 0u) {   // straggler
                const unsigned* rp = pub + (size_t)(t - 1) * NBLK + (lane << 2);
                while (!(q.x & 0x10000u)) { __builtin_amdgcn_s_sleep(1); q.x = load_rec4(rp + 0); }
                while (!(q.y & 0x10000u)) { __builtin_amdgcn_s_sleep(1); q.y = load_rec4(rp + 1); }
                while (!(q.z & 0x10000u)) { __builtin_amdgcn_s_sleep(1); q.z = load_rec4(rp + 2); }
                while (!(q.w & 0x10000u)) { __builtin_amdgcn_s_sleep(1); q.w = load_rec4(rp + 3); }
            }
            mlo = (q.x & 0xFFFFu) | ((q.y & 0xFFFFu) << 16);
            mhi = (q.z & 0xFFFFu) | ((q.w & 0xFFFFu) << 16);
        }
        unsigned long long m = ((unsigned long long)mhi << 32) | mlo;
        int myc = __popcll(m);

        // ---- gather: uniform 16-row blocks, u8 inner / u16 outer accs ----
        unsigned a0=0,a1=0,a2=0,a3=0,a4=0,a5=0,a6=0,a7=0;
        while (__any((int)(m != 0ull))) {
            unsigned be0=0, bo0=0, be1=0, bo1=0;
#pragma unroll
            for (int u = 0; u < 16; ++u) {
                int b = m ? (int)__builtin_ctzll(m) : bz;   // cndmask, no branch
                m &= m - 1;
                u32x2 w = wl[b];
                be0 += w.x & M4;  bo0 += (w.x >> 4) & M4;
                be1 += w.y & M4;  bo1 += (w.y >> 4) & M4;
            }
            // flush u8 batches into u16 accumulators
            a0 += be0 & M8;  a1 += (be0 >> 8) & M8;   // [n0,n4]   [n2,n6]
            a2 += bo0 & M8;  a3 += (bo0 >> 8) & M8;   // [n1,n5]   [n3,n7]
            a4 += be1 & M8;  a5 += (be1 >> 8) & M8;   // [n8,n12]  [n10,n14]
            a6 += bo1 & M8;  a7 += (bo1 >> 8) & M8;   // [n9,n13]  [n11,n15]
        }

        // ---- reduce-scatter butterfly: lane ends with its own neuron ----
        // stage s=1 on j0 (nibble parity): 8 -> 4
        unsigned e0 = (j0 ? a2 : a0) + __shfl_xor(j0 ? a0 : a2, 1);
        unsigned e1 = (j0 ? a3 : a1) + __shfl_xor(j0 ? a1 : a3, 1);
        unsigned e2 = (j0 ? a6 : a4) + __shfl_xor(j0 ? a4 : a6, 1);
        unsigned e3 = (j0 ? a7 : a5) + __shfl_xor(j0 ? a5 : a7, 1);
        // stage s=2 on j1: 4 -> 2
        unsigned f0 = (j1 ? e1 : e0) + __shfl_xor(j1 ? e0 : e1, 2);
        unsigned f1 = (j1 ? e3 : e2) + __shfl_xor(j1 ? e2 : e3, 2);
        // stage s=8 on j3: 2 -> 1
        unsigned g  = (j3 ? f1 : f0) + __shfl_xor(j3 ? f0 : f1, 8);
        // plain stages: sum remaining lane groups
        g += __shfl_xor(g, 4);
        g += __shfl_xor(g, 16);
        g += __shfl_xor(g, 32);
        // spike count n: plain butterfly
        myc += __shfl_xor(myc, 1);  myc += __shfl_xor(myc, 2);
        myc += __shfl_xor(myc, 4);  myc += __shfl_xor(myc, 8);
        myc += __shfl_xor(myc, 16); myc += __shfl_xor(myc, 32);

        int field = (int)((g >> ((j & 4) << 2)) & 0xFFFFu);
        int fb = field - 8 * myc;

        synv = (synv - (synv >> 4)) + in_cur + fb;   // syn(t)
    }
}

// ---------------------------------------------------------------------------
// ro[t][o] = sum_{k in spikes(t)} w2[o][k]; records: 0x10000|mask16
__global__ __launch_bounds__(256) void k_rocur(
    const int* __restrict__ w2,                // [N_OUT][N_HID]
    const unsigned* __restrict__ pub,
    int* __restrict__ ro)                      // [T][N_OUT]
{
    const int t = blockIdx.x;
    const int tid = threadIdx.x;
    __shared__ unsigned short s_list[N_HID];
    __shared__ int s_red[32][8];
    __shared__ int s_n;
    if (tid < 64) {
        const unsigned* rp = pub + (size_t)t * NBLK + (tid << 2);
        unsigned long long m =
            (unsigned long long)((rp[0] & 0xFFFFu) | ((rp[1] & 0xFFFFu) << 16)) |
            ((unsigned long long)((rp[2] & 0xFFFFu) | ((rp[3] & 0xFFFFu) << 16)) << 32);
        int cnt = __popcll(m);
        int inc = cnt;
#pragma unroll
        for (int d = 1; d < 64; d <<= 1) {
            int v = __shfl_up(inc, d);
            if (tid >= d) inc += v;
        }
        int p = inc - cnt;
        while (m) {
            s_list[p++] = (unsigned short)((tid << 6) | __builtin_ctzll(m));
            m &= m - 1;
        }
        if (tid == 63) s_n = inc;
    }
    __syncthreads();
    const int n = s_n;
    const int o = tid >> 3;
    const int r = tid & 7;
    if (o < N_OUT) {
        int acc = 0;
        for (int jj = r; jj < n; jj += 8) acc += w2[(size_t)o * N_HID + s_list[jj]];
        s_red[o][r] = acc;
    }
    __syncthreads();
    if (tid < N_OUT) {
        int acc = 0;
#pragma unroll
        for (int q = 0; q < 8; ++q) acc += s_red[tid][q];
        ro[(size_t)t * N_OUT + tid] = acc;
    }
}

// ---------------------------------------------------------------------------
// readout LIF scan; LDS-staged reads + coalesced stores. out [N_OUT][T] int32.
#define CH 250
__global__ __launch_bounds__(256) void k_scan(const int* __restrict__ ro,
                                              int* __restrict__ out)
{
    __shared__ int s_ro[CH * N_OUT];
    __shared__ int s_out[CH * N_OUT];
    const int tid = threadIdx.x;
    int rm = 0, rs = 0;
    for (int c = 0; c < T_STEPS / CH; ++c) {
        for (int i = tid; i < CH * N_OUT; i += 256)
            s_ro[i] = ro[c * CH * N_OUT + i];
        __syncthreads();
        if (tid < N_OUT) {
            for (int jj = 0; jj < CH; ++jj) {
                rm = (rm - (rm >> 3)) + rs;
                rs = (rs - (rs >> 4)) + s_ro[jj * N_OUT + tid];
                s_out[jj * N_OUT + tid] = rm;
            }
        }
        __syncthreads();
        for (int i = tid; i < CH * N_OUT; i += 256) {
            int o = i / CH, jj = i - o * CH;
            out[o * T_STEPS + c * CH + jj] = s_out[jj * N_OUT + o];
        }
        __syncthreads();
    }
}

// ---------------------------------------------------------------------------
extern "C" void kernel_launch(void* const* d_in, const int* in_sizes, int n_in,
                              void* d_out, int out_size, void* d_ws, size_t ws_size,
                              hipStream_t stream)
{
    const int* spk = (const int*)d_in[0];   // [1000][700]
    const int* w1  = (const int*)d_in[1];   // [4096][700]
    const int* v1  = (const int*)d_in[2];   // [4096][4096]
    const int* w2  = (const int*)d_in[3];   // [20][4096]
    int* out = (int*)d_out;                 // [20][1000] int32

    char* ws = (char*)d_ws;
    constexpr size_t SZ_PUB    = (size_t)(T_STEPS + 1) * NBLK * 4;  // 1,025,024
    constexpr size_t OFF_PUB   = 0;
    constexpr size_t OFF_INALL = OFF_PUB + SZ_PUB;                  // 8,192,000
    constexpr size_t OFF_V1N   = OFF_INALL + 8192000;               // 8,388,608
    constexpr size_t OFF_W1T   = OFF_V1N + 8388608;                 // 2,867,200
    constexpr size_t OFF_RO    = OFF_W1T + 2867200;                 // 80,000

    unsigned*       pub    = (unsigned*)(ws + OFF_PUB);
    short*          in_all = (short*)(ws + OFF_INALL);
    unsigned char*  v1n    = (unsigned char*)(ws + OFF_V1N);
    signed char*    w1t    = (signed char*)(ws + OFF_W1T);
    int*            ro     = (int*)(ws + OFF_RO);

    hipMemsetAsync(pub, 0, SZ_PUB, stream);   // clear flags (graph replays)

    dim3 tb(32, 8);
    k_prep_v1n<<<dim3(64, 256), 256, 0, stream>>>(v1, v1n);
    k_transpose_i8<<<dim3(22, 128), tb, 0, stream>>>(w1, w1t, N_HID, N_IN, N_HID);
    k_inall<<<dim3(16, 63), 256, 0, stream>>>(w1t, spk, in_all);

    k_main<<<dim3(NBLK), dim3(64), 0, stream>>>(in_all, (const u32x2*)v1n, pub);

    k_rocur<<<dim3(T_STEPS), 256, 0, stream>>>(w2, pub, ro);
    k_scan<<<1, 256, 0, stream>>>(ro, out);
}

// Round 10
// 1933.787 us; speedup vs baseline: 1.0093x; 1.0093x over previous
//
#include <hip/hip_runtime.h>

#define T_STEPS 1000
#define N_IN    700
#define N_HID   4096
#define N_OUT   20
#define NBLK    256   // main-loop blocks: 1 wave, 16 neurons each
#define NPB     16    // neurons per block

typedef unsigned int u32x4 __attribute__((ext_vector_type(4)));
typedef unsigned int u32x2 __attribute__((ext_vector_type(2)));

// 4B device-coherent record ops; waitcnt INSIDE asm (no live in-flight regs)
__device__ __forceinline__ unsigned load_rec4(const unsigned* p) {
    unsigned r;
    asm volatile("global_load_dword %0, %1, off sc0 sc1\n\t"
                 "s_waitcnt vmcnt(0)"
                 : "=v"(r) : "v"(p) : "memory");
    return r;
}
__device__ __forceinline__ void store_rec4(unsigned* p, unsigned v) {
    asm volatile("global_store_dword %0, %1, off sc0 sc1"
                 :: "v"(p), "v"(v) : "memory");
}

// ---------------------------------------------------------------------------
// w1t[c*4096 + r] = (int8) w1[r*700 + c]
__global__ __launch_bounds__(256) void k_transpose_i8(
    const int* __restrict__ in, signed char* __restrict__ out,
    int R, int C, int out_stride)
{
    __shared__ signed char tile[32][33];
    const int cx = blockIdx.x * 32;
    const int ry = blockIdx.y * 32;
    const int tx = threadIdx.x;
    const int ty = threadIdx.y;
#pragma unroll
    for (int r = 0; r < 4; ++r) {
        int row = ry + ty + r * 8;
        int col = cx + tx;
        if (row < R && col < C)
            tile[ty + r * 8][tx] = (signed char)in[(size_t)row * C + col];
    }
    __syncthreads();
#pragma unroll
    for (int r = 0; r < 4; ++r) {
        int c   = cx + ty + r * 8;
        int row = ry + tx;
        if (c < C && row < R)
            out[(size_t)c * out_stride + row] = tile[tx][ty + r * 8];
    }
}

// ---------------------------------------------------------------------------
// v1n[b][k] = 8B row: 16 nibbles = (v1[b*16+j][k] + 8), j=0..15
__global__ __launch_bounds__(256) void k_prep_v1n(
    const int* __restrict__ in, unsigned char* __restrict__ out)
{
    __shared__ unsigned char tile[16][64];
    const int k0 = blockIdx.x * 64;
    const int b  = blockIdx.y;
    const int t  = threadIdx.x;
    const int kk = t & 63;
#pragma unroll
    for (int r = 0; r < 4; ++r) {
        int hl = (t >> 6) + r * 4;     // 0..15
        tile[hl][kk] = (unsigned char)(in[(size_t)(b * NPB + hl) * N_HID + k0 + kk] + 8);
    }
    __syncthreads();
    if (t < 64) {
        unsigned w0 = 0, w1 = 0;
#pragma unroll
        for (int j = 0; j < 8; ++j) w0 |= (unsigned)tile[j][t] << (4 * j);
#pragma unroll
        for (int j = 0; j < 8; ++j) w1 |= (unsigned)tile[8 + j][t] << (4 * j);
        u32x2 v = {w0, w1};
        *(u32x2*)(out + ((size_t)b << 15) + ((size_t)(k0 + t) << 3)) = v;
    }
}

// ---------------------------------------------------------------------------
// in_all2[b][t][16]: in_all2[(h>>4)*T*16 + t*16 + (h&15)]
__global__ __launch_bounds__(256) void k_inall(
    const signed char* __restrict__ w1t,   // [N_IN][N_HID]
    const int* __restrict__ spk,           // [T][N_IN]
    short* __restrict__ in_all2)           // [256][T][16]
{
    __shared__ int s_spk[16][N_IN];
    const int t0 = blockIdx.y * 16;
    const int tcnt = min(16, T_STEPS - t0);
    const int tid = threadIdx.x;
    for (int b = 0; b < tcnt; ++b)
        for (int i = tid; i < N_IN; i += 256)
            s_spk[b][i] = spk[(size_t)(t0 + b) * N_IN + i];
    __syncthreads();
    const int h = blockIdx.x * 256 + tid;
    int acc[16];
#pragma unroll
    for (int b = 0; b < 16; ++b) acc[b] = 0;
    for (int i = 0; i < N_IN; ++i) {
        int w = (int)w1t[(size_t)i * N_HID + h];
#pragma unroll
        for (int b = 0; b < 16; ++b) acc[b] += w * s_spk[b][i];
    }
    const size_t base = (size_t)(h >> 4) * (T_STEPS * NPB) + (h & 15);
    for (int b = 0; b < tcnt; ++b)
        in_all2[base + (size_t)(t0 + b) * NPB] = (short)acc[b];
}

// ---------------------------------------------------------------------------
// Main LIF loop: 256 blocks x 1 wave x 16 neurons, weights (nibble) in LDS,
// no barriers. pub[r] = 0x10000|mask16(out(r)) published at top of iter r-1;
// row t prefetched via global_load_lds (1KB), drained by vmcnt(0) at next top.
// Gather: dual independent 32-bit chains (mlo/mhi), straight-line 16 pairs
// (dummy = broadcast zero row) + rare 4-pair remainder; u8 inner batches
// flushed to u16 accs every 8 pairs (16 rows x 15 max = 240 < 256, exact).
// Reduction: reduce-scatter butterfly — lane ends holding its own neuron.
__global__ __launch_bounds__(64) void k_main(
    const short* __restrict__ in_all2,      // [256][T][16]
    const u32x2* __restrict__ v1n,          // [256][4096] 8B nibble rows
    unsigned* __restrict__ pub)             // [T+1][256], zeroed
{
    const int lane = threadIdx.x;
    const int bid  = blockIdx.x;
    const int j    = lane & 15;             // mirrored neuron index

    __shared__ u32x2 s_w[N_HID + 1];        // 32KB weight slice + zero row
    __shared__ u32x4 s_rec[2][64];          // double-buffered record rows, 2KB

    // ---- load weight slice once (coalesced 8B x 64 lanes per iter) ----
    {
        const u32x2* src = v1n + ((size_t)bid << 12);
        for (int r = lane; r < N_HID; r += 64) s_w[r] = src[r];
        if (lane == 0) { u32x2 z = {0u, 0u}; s_w[N_HID] = z; }
    }
    asm volatile("s_waitcnt vmcnt(0) lgkmcnt(0)" ::: "memory");

    if (lane == 0) store_rec4(pub + bid, 0x10000u);   // row 0: out(0)=0

    // lookahead state: mm = m'(t), synv = syn(t-1), out_t = out(t)
    int mm = 0, synv = 0, out_t = 0;
    const short* in_base = in_all2 + (size_t)bid * (T_STEPS * NPB) + j;
    const u32x2* wl = s_w + (lane << 6);
    const int bz = N_HID - (lane << 6);     // per-lane index of the zero row
    const unsigned M4 = 0x0F0F0F0Fu, M8 = 0x00FF00FFu;
    const int j0 = j & 1, j1 = j & 2, j3 = j & 8;

    for (int t = 0; t < T_STEPS; ++t) {
        const int cur = t & 1;
        // drain prev iter's prefetch (all >=1 iter old)
        asm volatile("s_waitcnt vmcnt(0)" ::: "memory");
        __builtin_amdgcn_sched_barrier(0);

        // issue the record read EARLY: its ~120cy hides under publish below
        u32x4 q = s_rec[cur][lane];

        // ---- publish out(t+1) from local state ----
        int mem_t = (mm - (mm >> 3)) + synv;
        int mnext = out_t ? 0 : mem_t;
        int out_n = (mnext - 1 > 0) ? 1 : 0;
        unsigned om = (unsigned)__ballot(out_n) & 0xFFFFu;
        if (lane == 0) store_rec4(pub + (size_t)(t + 1) * NBLK + bid, 0x10000u | om);
        mm = mnext; out_t = out_n;

        int in_cur = (int)in_base[t * NPB];

        // ---- prefetch row t (for iter t+1): 64 lanes x 16B = 1KB ----
        __builtin_amdgcn_global_load_lds(
            (const void*)(pub + (size_t)t * NBLK + (lane << 2)),
            (void*)&s_rec[cur ^ 1][0], 16, 0, /*sc0|sc1*/ 17);

        // ---- consume row t-1: this lane's 4 records -> two 32-bit masks ----
        unsigned mlo = 0, mhi = 0;
        if (t > 0) {
            if (((q.x & q.y & q.z & q.w) & 0x10000u) == 0u) {   // straggler
                const unsigned* rp = pub + (size_t)(t - 1) * NBLK + (lane << 2);
                while (!(q.x & 0x10000u)) { __builtin_amdgcn_s_sleep(1); q.x = load_rec4(rp + 0); }
                while (!(q.y & 0x10000u)) { __builtin_amdgcn_s_sleep(1); q.y = load_rec4(rp + 1); }
                while (!(q.z & 0x10000u)) { __builtin_amdgcn_s_sleep(1); q.z = load_rec4(rp + 2); }
                while (!(q.w & 0x10000u)) { __builtin_amdgcn_s_sleep(1); q.w = load_rec4(rp + 3); }
            }
            mlo = (q.x & 0xFFFFu) | ((q.y & 0xFFFFu) << 16);
            mhi = (q.z & 0xFFFFu) | ((q.w & 0xFFFFu) << 16);
        }
        int myc = __popc(mlo) + __popc(mhi);        // slot spike count

        // ---- gather: straight-line 16 pairs + rare remainder ----
        unsigned a0=0,a1=0,a2=0,a3=0,a4=0,a5=0,a6=0,a7=0;
        {
            unsigned lo = mlo, hi = mhi;
#pragma unroll
            for (int half = 0; half < 2; ++half) {
                unsigned be0=0, bo0=0, be1=0, bo1=0;
#pragma unroll
                for (int u = 0; u < 8; ++u) {
                    int b0 = lo ? (int)__builtin_ctz(lo) : bz;
                    int b1 = hi ? (int)(32 + __builtin_ctz(hi)) : bz;
                    lo &= lo - 1;  hi &= hi - 1;
                    u32x2 w0 = wl[b0];
                    u32x2 w1 = wl[b1];
                    be0 += w0.x & M4;  bo0 += (w0.x >> 4) & M4;
                    be1 += w0.y & M4;  bo1 += (w0.y >> 4) & M4;
                    be0 += w1.x & M4;  bo0 += (w1.x >> 4) & M4;
                    be1 += w1.y & M4;  bo1 += (w1.y >> 4) & M4;
                }
                a0 += be0 & M8;  a1 += (be0 >> 8) & M8;
                a2 += bo0 & M8;  a3 += (bo0 >> 8) & M8;
                a4 += be1 & M8;  a5 += (be1 >> 8) & M8;
                a6 += bo1 & M8;  a7 += (bo1 >> 8) & M8;
            }
            while (lo | hi) {                        // >16 bits in a chain: rare
                unsigned be0=0, bo0=0, be1=0, bo1=0;
#pragma unroll
                for (int u = 0; u < 4; ++u) {
                    int b0 = lo ? (int)__builtin_ctz(lo) : bz;
                    int b1 = hi ? (int)(32 + __builtin_ctz(hi)) : bz;
                    lo &= lo - 1;  hi &= hi - 1;
                    u32x2 w0 = wl[b0];
                    u32x2 w1 = wl[b1];
                    be0 += w0.x & M4;  bo0 += (w0.x >> 4) & M4;
                    be1 += w0.y & M4;  bo1 += (w0.y >> 4) & M4;
                    be0 += w1.x & M4;  bo0 += (w1.x >> 4) & M4;
                    be1 += w1.y & M4;  bo1 += (w1.y >> 4) & M4;
                }
                a0 += be0 & M8;  a1 += (be0 >> 8) & M8;
                a2 += bo0 & M8;  a3 += (bo0 >> 8) & M8;
                a4 += be1 & M8;  a5 += (be1 >> 8) & M8;
                a6 += bo1 & M8;  a7 += (bo1 >> 8) & M8;
            }
        }

        // ---- reduce-scatter butterfly: lane ends with its own neuron ----
        unsigned e0 = (j0 ? a2 : a0) + __shfl_xor(j0 ? a0 : a2, 1);
        unsigned e1 = (j0 ? a3 : a1) + __shfl_xor(j0 ? a1 : a3, 1);
        unsigned e2 = (j0 ? a6 : a4) + __shfl_xor(j0 ? a4 : a6, 1);
        unsigned e3 = (j0 ? a7 : a5) + __shfl_xor(j0 ? a5 : a7, 1);
        unsigned f0 = (j1 ? e1 : e0) + __shfl_xor(j1 ? e0 : e1, 2);
        unsigned f1 = (j1 ? e3 : e2) + __shfl_xor(j1 ? e2 : e3, 2);
        unsigned g  = (j3 ? f1 : f0) + __shfl_xor(j3 ? f0 : f1, 8);
        g += __shfl_xor(g, 4);
        g += __shfl_xor(g, 16);
        g += __shfl_xor(g, 32);
        myc += __shfl_xor(myc, 1);  myc += __shfl_xor(myc, 2);
        myc += __shfl_xor(myc, 4);  myc += __shfl_xor(myc, 8);
        myc += __shfl_xor(myc, 16); myc += __shfl_xor(myc, 32);

        int field = (int)((g >> ((j & 4) << 2)) & 0xFFFFu);
        int fb = field - 8 * myc;

        synv = (synv - (synv >> 4)) + in_cur + fb;   // syn(t)
    }
}

// ---------------------------------------------------------------------------
// ro[t][o] = sum_{k in spikes(t)} w2[o][k]; records: 0x10000|mask16
__global__ __launch_bounds__(256) void k_rocur(
    const int* __restrict__ w2,                // [N_OUT][N_HID]
    const unsigned* __restrict__ pub,
    int* __restrict__ ro)                      // [T][N_OUT]
{
    const int t = blockIdx.x;
    const int tid = threadIdx.x;
    __shared__ unsigned short s_list[N_HID];
    __shared__ int s_red[32][8];
    __shared__ int s_n;
    if (tid < 64) {
        const unsigned* rp = pub + (size_t)t * NBLK + (tid << 2);
        unsigned long long m =
            (unsigned long long)((rp[0] & 0xFFFFu) | ((rp[1] & 0xFFFFu) << 16)) |
            ((unsigned long long)((rp[2] & 0xFFFFu) | ((rp[3] & 0xFFFFu) << 16)) << 32);
        int cnt = __popcll(m);
        int inc = cnt;
#pragma unroll
        for (int d = 1; d < 64; d <<= 1) {
            int v = __shfl_up(inc, d);
            if (tid >= d) inc += v;
        }
        int p = inc - cnt;
        while (m) {
            s_list[p++] = (unsigned short)((tid << 6) | __builtin_ctzll(m));
            m &= m - 1;
        }
        if (tid == 63) s_n = inc;
    }
    __syncthreads();
    const int n = s_n;
    const int o = tid >> 3;
    const int r = tid & 7;
    if (o < N_OUT) {
        int acc = 0;
        for (int jj = r; jj < n; jj += 8) acc += w2[(size_t)o * N_HID + s_list[jj]];
        s_red[o][r] = acc;
    }
    __syncthreads();
    if (tid < N_OUT) {
        int acc = 0;
#pragma unroll
        for (int q = 0; q < 8; ++q) acc += s_red[tid][q];
        ro[(size_t)t * N_OUT + tid] = acc;
    }
}

// ---------------------------------------------------------------------------
// readout LIF scan; LDS-staged reads + coalesced stores. out [N_OUT][T] int32.
#define CH 250
__global__ __launch_bounds__(256) void k_scan(const int* __restrict__ ro,
                                              int* __restrict__ out)
{
    __shared__ int s_ro[CH * N_OUT];
    __shared__ int s_out[CH * N_OUT];
    const int tid = threadIdx.x;
    int rm = 0, rs = 0;
    for (int c = 0; c < T_STEPS / CH; ++c) {
        for (int i = tid; i < CH * N_OUT; i += 256)
            s_ro[i] = ro[c * CH * N_OUT + i];
        __syncthreads();
        if (tid < N_OUT) {
            for (int jj = 0; jj < CH; ++jj) {
                rm = (rm - (rm >> 3)) + rs;
                rs = (rs - (rs >> 4)) + s_ro[jj * N_OUT + tid];
                s_out[jj * N_OUT + tid] = rm;
            }
        }
        __syncthreads();
        for (int i = tid; i < CH * N_OUT; i += 256) {
            int o = i / CH, jj = i - o * CH;
            out[o * T_STEPS + c * CH + jj] = s_out[jj * N_OUT + o];
        }
        __syncthreads();
    }
}

// ---------------------------------------------------------------------------
extern "C" void kernel_launch(void* const* d_in, const int* in_sizes, int n_in,
                              void* d_out, int out_size, void* d_ws, size_t ws_size,
                              hipStream_t stream)
{
    const int* spk = (const int*)d_in[0];   // [1000][700]
    const int* w1  = (const int*)d_in[1];   // [4096][700]
    const int* v1  = (const int*)d_in[2];   // [4096][4096]
    const int* w2  = (const int*)d_in[3];   // [20][4096]
    int* out = (int*)d_out;                 // [20][1000] int32

    char* ws = (char*)d_ws;
    constexpr size_t SZ_PUB    = (size_t)(T_STEPS + 1) * NBLK * 4;  // 1,025,024
    constexpr size_t OFF_PUB   = 0;
    constexpr size_t OFF_INALL = OFF_PUB + SZ_PUB;                  // 8,192,000
    constexpr size_t OFF_V1N   = OFF_INALL + 8192000;               // 8,388,608
    constexpr size_t OFF_W1T   = OFF_V1N + 8388608;                 // 2,867,200
    constexpr size_t OFF_RO    = OFF_W1T + 2867200;                 // 80,000

    unsigned*       pub    = (unsigned*)(ws + OFF_PUB);
    short*          in_all = (short*)(ws + OFF_INALL);
    unsigned char*  v1n    = (unsigned char*)(ws + OFF_V1N);
    signed char*    w1t    = (signed char*)(ws + OFF_W1T);
    int*            ro     = (int*)(ws + OFF_RO);

    hipMemsetAsync(pub, 0, SZ_PUB, stream);   // clear flags (graph replays)

    dim3 tb(32, 8);
    k_prep_v1n<<<dim3(64, 256), 256, 0, stream>>>(v1, v1n);
    k_transpose_i8<<<dim3(22, 128), tb, 0, stream>>>(w1, w1t, N_HID, N_IN, N_HID);
    k_inall<<<dim3(16, 63), 256, 0, stream>>>(w1t, spk, in_all);

    k_main<<<dim3(NBLK), dim3(64), 0, stream>>>(in_all, (const u32x2*)v1n, pub);

    k_rocur<<<dim3(T_STEPS), 256, 0, stream>>>(w2, pub, ro);
    k_scan<<<1, 256, 0, stream>>>(ro, out);
}